// Round 2
// baseline (186.483 us; speedup 1.0000x reference)
//
#include <hip/hip_runtime.h>

// GeneSymbolCNN: embed(67x32, pad0) -> conv1d k=2/3/4 (32ch) + ReLU + max_t
//                -> concat(96) -> 96x96 linear + ReLU.
// Conv-over-embedding factors into per-token tables:
//   T_{k,h}[v][c] = sum_e embed[v,e] * w_k[c,e,h]  (bias folded into h=0)
//   y_k[b,c,p]    = sum_h T_{k,h}[x[b,p+h]][c]
//
// R2 change: conflict-free LDS. Table rows stored UNPADDED at 32 floats
// (128 B = 8 bank-groups) so bank-group = chunk index only (row drops out).
// Lane l reads chunk (q + (l&7))&7 at step q -> Latin square over groups,
// zero bank conflicts for arbitrary token data. Accumulator slots are
// channel-rotated per lane; un-rotated by a 3-stage barrel shifter
// (compile-time indices -> v_cndmask, no scratch) before the projection.

#define VOCABSZ 67
#define EMBSZ   32
#define NCH     32
#define NFEAT   96
#define SEQL    16
#define BATCH   131072
#define VT      (VOCABSZ * NCH)       // 2144 floats per table (no pad)
#define NTAB    9
#define TABF    (NTAB * VT)           // 19296 floats = 77184 bytes

// ---------------- kernel 1: build the 9 per-token tables into d_ws ----------
__global__ __launch_bounds__(256) void build_tables(
    const float* __restrict__ embed,
    const float* __restrict__ w2, const float* __restrict__ b2,
    const float* __restrict__ w3, const float* __restrict__ b3,
    const float* __restrict__ w4, const float* __restrict__ b4,
    float* __restrict__ tabs)
{
    int idx = blockIdx.x * 256 + threadIdx.x;
    if (idx >= NTAB * VOCABSZ * NCH) return;
    int c = idx & 31;
    int t = idx >> 5;            // 0..602 = j*67 + v
    int j = t / VOCABSZ;
    int v = t - j * VOCABSZ;

    const float* w; const float* bias; int k, h;
    if (j < 2)      { w = w2; k = 2; h = j;     bias = (h == 0) ? b2 : nullptr; }
    else if (j < 5) { w = w3; k = 3; h = j - 2; bias = (h == 0) ? b3 : nullptr; }
    else            { w = w4; k = 4; h = j - 5; bias = (h == 0) ? b4 : nullptr; }

    float acc = bias ? bias[c] : 0.0f;
    if (v != 0) {                 // padding_idx=0: embedding row 0 is zero
        #pragma unroll
        for (int e = 0; e < EMBSZ; ++e)
            acc += embed[v * EMBSZ + e] * w[(c * EMBSZ + e) * k + h];
    }
    tabs[(j * VOCABSZ + v) * NCH + c] = acc;
}

// ---------------- kernel 2: fused conv-as-lookup + max + projection ---------
__device__ __forceinline__ float4 max4(float4 a, float4 b) {
    return make_float4(fmaxf(a.x, b.x), fmaxf(a.y, b.y),
                       fmaxf(a.z, b.z), fmaxf(a.w, b.w));
}
__device__ __forceinline__ float4 add4(float4 a, float4 b) {
    return make_float4(a.x + b.x, a.y + b.y, a.z + b.z, a.w + b.w);
}

__global__ __launch_bounds__(512) void fused_cnn(
    const int*   __restrict__ x,
    const float* __restrict__ tabs,
    const float* __restrict__ pw,
    const float* __restrict__ pb,
    float*       __restrict__ out)
{
    extern __shared__ __align__(16) float lds[];
    const int tid = threadIdx.x;
    {
        const float4* src = reinterpret_cast<const float4*>(tabs);
        float4* dst = reinterpret_cast<float4*>(lds);
        #pragma unroll
        for (int i = 0; i < TABF / 4; i += 512)
            dst[i + tid] = src[i + tid];
        // TABF/4 = 4824 = 9*512 + 216
        if (tid < 216) dst[4608 + tid] = src[4608 + tid];
    }
    __syncthreads();

    const int row = blockIdx.x * 512 + tid;     // grid exact: 256*512 = B
    const int rot = tid & 7;                    // lane&7 (bank-group rotation)

    const int4* xp = reinterpret_cast<const int4*>(x + row * SEQL);
    int4 q0 = xp[0], q1 = xp[1], q2 = xp[2], q3 = xp[3];
    int voff[16];
    voff[ 0] = q0.x * NCH; voff[ 1] = q0.y * NCH; voff[ 2] = q0.z * NCH; voff[ 3] = q0.w * NCH;
    voff[ 4] = q1.x * NCH; voff[ 5] = q1.y * NCH; voff[ 6] = q1.z * NCH; voff[ 7] = q1.w * NCH;
    voff[ 8] = q2.x * NCH; voff[ 9] = q2.y * NCH; voff[10] = q2.z * NCH; voff[11] = q2.w * NCH;
    voff[12] = q3.x * NCH; voff[13] = q3.y * NCH; voff[14] = q3.z * NCH; voff[15] = q3.w * NCH;

    float4 r2[8], r3[8], r4[8];
    #pragma unroll
    for (int s = 0; s < 8; ++s) {
        r2[s] = make_float4(0.f, 0.f, 0.f, 0.f);
        r3[s] = r2[s]; r4[s] = r2[s];
    }

    // slot q accumulates channel-chunk (q+rot)&7; bank-group = chunk -> no
    // conflicts (Latin square across the wave at every read).
    #pragma unroll
    for (int q = 0; q < 8; ++q) {
        const int qe = ((q + rot) & 7) * 4;     // float offset within row
        int a[16];
        #pragma unroll
        for (int p = 0; p < SEQL; ++p) a[p] = voff[p] + qe;

        #pragma unroll
        for (int p = 0; p < 15; ++p) {          // conv2: tables 0,1
            float4 u = *reinterpret_cast<const float4*>(lds + 0 * VT + a[p]);
            float4 w = *reinterpret_cast<const float4*>(lds + 1 * VT + a[p + 1]);
            r2[q] = max4(r2[q], add4(u, w));
        }
        #pragma unroll
        for (int p = 0; p < 14; ++p) {          // conv3: tables 2,3,4
            float4 u = *reinterpret_cast<const float4*>(lds + 2 * VT + a[p]);
            float4 w = *reinterpret_cast<const float4*>(lds + 3 * VT + a[p + 1]);
            float4 s = *reinterpret_cast<const float4*>(lds + 4 * VT + a[p + 2]);
            r3[q] = max4(r3[q], add4(add4(u, w), s));
        }
        #pragma unroll
        for (int p = 0; p < 13; ++p) {          // conv4: tables 5,6,7,8
            float4 u = *reinterpret_cast<const float4*>(lds + 5 * VT + a[p]);
            float4 w = *reinterpret_cast<const float4*>(lds + 6 * VT + a[p + 1]);
            float4 s = *reinterpret_cast<const float4*>(lds + 7 * VT + a[p + 2]);
            float4 r = *reinterpret_cast<const float4*>(lds + 8 * VT + a[p + 3]);
            r4[q] = max4(r4[q], add4(add4(u, w), add4(s, r)));
        }
    }

    // Barrel-rotate: canon[c] = slot[(c-rot)&7]. 3 stages, compile-time idx.
    #pragma unroll
    for (int s = 1; s <= 4; s <<= 1) {
        const bool doit = (rot & s) != 0;
        float4 t2[8], t3[8], t4[8];
        #pragma unroll
        for (int c = 0; c < 8; ++c) {
            t2[c] = doit ? r2[(c - s) & 7] : r2[c];
            t3[c] = doit ? r3[(c - s) & 7] : r3[c];
            t4[c] = doit ? r4[(c - s) & 7] : r4[c];
        }
        #pragma unroll
        for (int c = 0; c < 8; ++c) { r2[c] = t2[c]; r3[c] = t3[c]; r4[c] = t4[c]; }
    }

    float feat[NFEAT];
    #pragma unroll
    for (int c = 0; c < 8; ++c) {
        feat[c*4+0]  = r2[c].x; feat[c*4+1]  = r2[c].y; feat[c*4+2]  = r2[c].z; feat[c*4+3]  = r2[c].w;
        feat[32+c*4+0] = r3[c].x; feat[32+c*4+1] = r3[c].y; feat[32+c*4+2] = r3[c].z; feat[32+c*4+3] = r3[c].w;
        feat[64+c*4+0] = r4[c].x; feat[64+c*4+1] = r4[c].y; feat[64+c*4+2] = r4[c].z; feat[64+c*4+3] = r4[c].w;
    }

    // projection: out[row,o] = relu(sum_f feat[f]*pw[o,f] + pb[o])
    // pw/pb wave-uniform -> s_load + v_fmac with SGPR operand.
    float* orow = out + (size_t)row * NFEAT;
    #pragma unroll 1
    for (int ob = 0; ob < NFEAT; ob += 8) {
        float acc[8];
        #pragma unroll
        for (int k = 0; k < 8; ++k) acc[k] = pb[ob + k];
        #pragma unroll
        for (int f = 0; f < NFEAT; ++f) {
            #pragma unroll
            for (int k = 0; k < 8; ++k) acc[k] += feat[f] * pw[(ob + k) * NFEAT + f];
        }
        float4 o0 = make_float4(fmaxf(acc[0], 0.f), fmaxf(acc[1], 0.f),
                                fmaxf(acc[2], 0.f), fmaxf(acc[3], 0.f));
        float4 o1 = make_float4(fmaxf(acc[4], 0.f), fmaxf(acc[5], 0.f),
                                fmaxf(acc[6], 0.f), fmaxf(acc[7], 0.f));
        *reinterpret_cast<float4*>(orow + ob)     = o0;
        *reinterpret_cast<float4*>(orow + ob + 4) = o1;
    }
}

extern "C" void kernel_launch(void* const* d_in, const int* in_sizes, int n_in,
                              void* d_out, int out_size, void* d_ws, size_t ws_size,
                              hipStream_t stream)
{
    const int*   x     = (const int*)  d_in[0];
    const float* embed = (const float*)d_in[1];
    const float* w2    = (const float*)d_in[2];
    const float* b2    = (const float*)d_in[3];
    const float* w3    = (const float*)d_in[4];
    const float* b3    = (const float*)d_in[5];
    const float* w4    = (const float*)d_in[6];
    const float* b4    = (const float*)d_in[7];
    const float* pw    = (const float*)d_in[8];
    const float* pb    = (const float*)d_in[9];
    float* out  = (float*)d_out;
    float* tabs = (float*)d_ws;           // 77184 bytes of scratch

    build_tables<<<(NTAB * VOCABSZ * NCH + 255) / 256, 256, 0, stream>>>(
        embed, w2, b2, w3, b3, w4, b4, tabs);

    (void)hipFuncSetAttribute((const void*)fused_cnn,
                              hipFuncAttributeMaxDynamicSharedMemorySize,
                              TABF * 4);
    fused_cnn<<<BATCH / 512, 512, TABF * 4, stream>>>(x, tabs, pw, pb, out);
}

// Round 3
// 71.156 us; speedup vs baseline: 2.6208x; 2.6208x over previous
//
#include <hip/hip_runtime.h>
#include <hip/hip_fp16.h>

// GeneSymbolCNN: embed(67x32, pad0) -> conv1d k=2/3/4 (32ch) + ReLU + max_t
//                -> concat(96) -> 96x96 linear + ReLU.
// Conv-over-embedding factors into per-token tables:
//   T_{k,h}[v][c] = sum_e embed[v,e] * w_k[c,e,h]  (bias folded into h=0)
// R3: tables in f16 (38.6 KB LDS, half the ds_read_b128 count), packed-f16
// conv accumulate (48 VGPR acc), projection via v_dot2_f32_f16 with f32
// accumulation and pre-packed half2 pw. Chunk lane-rotation (q + tid&3)
// spreads reads over 16 banks; un-rotated by compile-time-indexed selects.
// Register discipline: peak live ~110 VGPR (R2 spilled at ~290 -> 238 MB
// scratch traffic; that was the 2x regression).

#define VOCABSZ 67
#define EMBSZ   32
#define NCH     32
#define NFEAT   96
#define SEQL    16
#define BATCH   131072
#define NTAB    9
#define VTB     (VOCABSZ * NCH * 2)        // bytes per table = 4288
#define TABU    (NTAB * VOCABSZ * NCH / 2) // u32 words of f16 tables = 9648
#define TABBYTES (TABU * 4)                // 38592
#define PWOFF   TABU                       // u32 offset of packed pw in ws
#define NFP     (NFEAT / 2)                // 48 feature pairs
#define NPW     (NFEAT * NFP)              // 4608 packed pw words

typedef _Float16 v2h __attribute__((ext_vector_type(2)));
typedef _Float16 v8h __attribute__((ext_vector_type(8)));

__device__ __forceinline__ unsigned packh2(float a, float b) {
    v2h p; p[0] = (_Float16)a; p[1] = (_Float16)b;
    return __builtin_bit_cast(unsigned, p);
}

__device__ __forceinline__ float dot2acc(v2h a, v2h b, float c) {
#if __has_builtin(__builtin_amdgcn_fdot2)
    return __builtin_amdgcn_fdot2(a, b, c, false);   // v_dot2_f32_f16
#else
    return c + (float)a[0] * (float)b[0] + (float)a[1] * (float)b[1];
#endif
}

// ------------- kernel 1: f16 tables + packed pw into d_ws ------------------
__global__ __launch_bounds__(256) void build_tables(
    const float* __restrict__ embed,
    const float* __restrict__ w2, const float* __restrict__ b2,
    const float* __restrict__ w3, const float* __restrict__ b3,
    const float* __restrict__ w4, const float* __restrict__ b4,
    const float* __restrict__ pw,
    unsigned* __restrict__ ws)
{
    int idx = blockIdx.x * 256 + threadIdx.x;
    if (idx < TABU) {                      // one half2 (2 channels) per thread
        int cp = idx & 15;                 // channel pair 0..15
        int t  = idx >> 4;                 // j*67 + v
        int j  = t / VOCABSZ;
        int v  = t - j * VOCABSZ;
        const float* w; const float* bias; int k, h;
        if (j < 2)      { w = w2; k = 2; h = j;     bias = (h == 0) ? b2 : nullptr; }
        else if (j < 5) { w = w3; k = 3; h = j - 2; bias = (h == 0) ? b3 : nullptr; }
        else            { w = w4; k = 4; h = j - 5; bias = (h == 0) ? b4 : nullptr; }
        int c0 = 2 * cp;
        float a0 = bias ? bias[c0]     : 0.0f;
        float a1 = bias ? bias[c0 + 1] : 0.0f;
        if (v != 0) {                      // padding_idx=0: row 0 is zeros
            #pragma unroll
            for (int e = 0; e < EMBSZ; ++e) {
                float ev = embed[v * EMBSZ + e];
                a0 += ev * w[((c0    ) * EMBSZ + e) * k + h];
                a1 += ev * w[((c0 + 1) * EMBSZ + e) * k + h];
            }
        }
        ws[t * 16 + cp] = packh2(a0, a1);
    } else if (idx < TABU + NPW) {         // packed pw: pwh[o][fp]
        int i  = idx - TABU;
        int o  = i / NFP;
        int fp = i - o * NFP;
        ws[PWOFF + i] = packh2(pw[o * NFEAT + 2 * fp], pw[o * NFEAT + 2 * fp + 1]);
    }
}

// ------------- kernel 2: fused conv-as-lookup + max + projection -----------
__device__ __forceinline__ void unrot(v2h (&m)[16], bool r1, bool r2) {
    // canon[c] = m[(c - rot) & 3] groupwise (groups of 4 half2 slots)
    v2h t[16];
    #pragma unroll
    for (int j = 0; j < 4; ++j) {
        t[0 + j]  = r1 ? m[12 + j] : m[0 + j];
        t[4 + j]  = r1 ? m[0 + j]  : m[4 + j];
        t[8 + j]  = r1 ? m[4 + j]  : m[8 + j];
        t[12 + j] = r1 ? m[8 + j]  : m[12 + j];
    }
    #pragma unroll
    for (int j = 0; j < 4; ++j) {
        m[0 + j]  = r2 ? t[8 + j]  : t[0 + j];
        m[4 + j]  = r2 ? t[12 + j] : t[4 + j];
        m[8 + j]  = r2 ? t[0 + j]  : t[8 + j];
        m[12 + j] = r2 ? t[4 + j]  : t[12 + j];
    }
}

#define MAXACC(M, Q, S) \
    M[4*(Q)+0] = __builtin_elementwise_max(M[4*(Q)+0], __builtin_shufflevector(S, S, 0, 1)); \
    M[4*(Q)+1] = __builtin_elementwise_max(M[4*(Q)+1], __builtin_shufflevector(S, S, 2, 3)); \
    M[4*(Q)+2] = __builtin_elementwise_max(M[4*(Q)+2], __builtin_shufflevector(S, S, 4, 5)); \
    M[4*(Q)+3] = __builtin_elementwise_max(M[4*(Q)+3], __builtin_shufflevector(S, S, 6, 7));

__global__ __launch_bounds__(512) void fused_cnn(
    const int*      __restrict__ x,
    const unsigned* __restrict__ ws,
    const float*    __restrict__ pb,
    float*          __restrict__ out)
{
    extern __shared__ __align__(16) char ldsraw[];
    const int tid = threadIdx.x;
    {   // stage 38592 B of f16 tables: 2412 float4
        const float4* src = reinterpret_cast<const float4*>(ws);
        float4* dst = reinterpret_cast<float4*>(ldsraw);
        dst[tid]        = src[tid];
        dst[512 + tid]  = src[512 + tid];
        dst[1024 + tid] = src[1024 + tid];
        dst[1536 + tid] = src[1536 + tid];
        if (tid < 364) dst[2048 + tid] = src[2048 + tid];
    }
    __syncthreads();

    const int row = blockIdx.x * 512 + tid;      // grid exact: 256*512 = B
    const int rot = tid & 3;
    const char* base = ldsraw;

    const int4* xp = reinterpret_cast<const int4*>(x + row * SEQL);
    int4 q0 = xp[0], q1 = xp[1], q2 = xp[2], q3 = xp[3];
    int vb[16];                                   // byte offset of table row
    vb[ 0] = q0.x << 6; vb[ 1] = q0.y << 6; vb[ 2] = q0.z << 6; vb[ 3] = q0.w << 6;
    vb[ 4] = q1.x << 6; vb[ 5] = q1.y << 6; vb[ 6] = q1.z << 6; vb[ 7] = q1.w << 6;
    vb[ 8] = q2.x << 6; vb[ 9] = q2.y << 6; vb[10] = q2.z << 6; vb[11] = q2.w << 6;
    vb[12] = q3.x << 6; vb[13] = q3.y << 6; vb[14] = q3.z << 6; vb[15] = q3.w << 6;

    v2h m2[16], m3[16], m4[16];
    #pragma unroll
    for (int i = 0; i < 16; ++i) { m2[i] = 0; m3[i] = 0; m4[i] = 0; }

    #pragma unroll
    for (int q = 0; q < 4; ++q) {                 // 16B chunk step, lane-rotated
        const int co = ((q + rot) & 3) << 4;
        int ap[16];
        #pragma unroll
        for (int p = 0; p < 16; ++p) ap[p] = vb[p] + co;

        #pragma unroll
        for (int p = 0; p < 15; ++p) {            // conv2: tables 0,1
            v8h a0 = *reinterpret_cast<const v8h*>(base + 0 * VTB + ap[p]);
            v8h a1 = *reinterpret_cast<const v8h*>(base + 1 * VTB + ap[p + 1]);
            v8h s = a0 + a1;
            MAXACC(m2, q, s)
        }
        #pragma unroll
        for (int p = 0; p < 14; ++p) {            // conv3: tables 2,3,4
            v8h a0 = *reinterpret_cast<const v8h*>(base + 2 * VTB + ap[p]);
            v8h a1 = *reinterpret_cast<const v8h*>(base + 3 * VTB + ap[p + 1]);
            v8h a2 = *reinterpret_cast<const v8h*>(base + 4 * VTB + ap[p + 2]);
            v8h s = a0 + a1 + a2;
            MAXACC(m3, q, s)
        }
        #pragma unroll
        for (int p = 0; p < 13; ++p) {            // conv4: tables 5,6,7,8
            v8h a0 = *reinterpret_cast<const v8h*>(base + 5 * VTB + ap[p]);
            v8h a1 = *reinterpret_cast<const v8h*>(base + 6 * VTB + ap[p + 1]);
            v8h a2 = *reinterpret_cast<const v8h*>(base + 7 * VTB + ap[p + 2]);
            v8h a3 = *reinterpret_cast<const v8h*>(base + 8 * VTB + ap[p + 3]);
            v8h s = (a0 + a1) + (a2 + a3);
            MAXACC(m4, q, s)
        }
    }

    const bool r1 = (rot & 1) != 0, r2b = (rot & 2) != 0;
    unrot(m2, r1, r2b);
    unrot(m3, r1, r2b);
    unrot(m4, r1, r2b);

    // projection: acc f32, v_dot2_f32_f16 over packed feature pairs.
    const unsigned* __restrict__ pwh = ws + PWOFF;  // wave-uniform -> s_load
    float* orow = out + (size_t)row * NFEAT;
    #pragma unroll 1
    for (int ob = 0; ob < NFEAT; ob += 8) {
        float acc[8];
        #pragma unroll
        for (int k = 0; k < 8; ++k) acc[k] = pb[ob + k];
        #pragma unroll
        for (int fp = 0; fp < NFP; ++fp) {
            v2h fv = (fp < 16) ? m2[fp] : ((fp < 32) ? m3[fp - 16] : m4[fp - 32]);
            #pragma unroll
            for (int k = 0; k < 8; ++k) {
                v2h wv = __builtin_bit_cast(v2h, pwh[(ob + k) * NFP + fp]);
                acc[k] = dot2acc(fv, wv, acc[k]);
            }
        }
        float4 o0 = make_float4(fmaxf(acc[0], 0.f), fmaxf(acc[1], 0.f),
                                fmaxf(acc[2], 0.f), fmaxf(acc[3], 0.f));
        float4 o1 = make_float4(fmaxf(acc[4], 0.f), fmaxf(acc[5], 0.f),
                                fmaxf(acc[6], 0.f), fmaxf(acc[7], 0.f));
        *reinterpret_cast<float4*>(orow + ob)     = o0;
        *reinterpret_cast<float4*>(orow + ob + 4) = o1;
    }
}

extern "C" void kernel_launch(void* const* d_in, const int* in_sizes, int n_in,
                              void* d_out, int out_size, void* d_ws, size_t ws_size,
                              hipStream_t stream)
{
    const int*   x     = (const int*)  d_in[0];
    const float* embed = (const float*)d_in[1];
    const float* w2    = (const float*)d_in[2];
    const float* b2    = (const float*)d_in[3];
    const float* w3    = (const float*)d_in[4];
    const float* b3    = (const float*)d_in[5];
    const float* w4    = (const float*)d_in[6];
    const float* b4    = (const float*)d_in[7];
    const float* pw    = (const float*)d_in[8];
    const float* pb    = (const float*)d_in[9];
    float* out = (float*)d_out;
    unsigned* ws = (unsigned*)d_ws;      // 9648 + 4608 u32 = 57 KB used

    build_tables<<<(TABU + NPW + 255) / 256, 256, 0, stream>>>(
        embed, w2, b2, w3, b3, w4, b4, pw, ws);

    (void)hipFuncSetAttribute((const void*)fused_cnn,
                              hipFuncAttributeMaxDynamicSharedMemorySize,
                              TABBYTES);
    fused_cnn<<<BATCH / 512, 512, TABBYTES, stream>>>(x, ws, pb, out);
}

// Round 4
// 66.044 us; speedup vs baseline: 2.8236x; 1.0774x over previous
//
#include <hip/hip_runtime.h>
#include <hip/hip_fp16.h>

// GeneSymbolCNN: embed(67x32, pad0) -> conv1d k=2/3/4 (32ch) + ReLU + max_t
//                -> concat(96) -> 96x96 linear + ReLU.
// Conv-over-embedding factors into per-token f16 tables:
//   T_{k,h}[v][c] = sum_e embed[v,e] * w_k[c,e,h]  (bias folded into h=0)
// R4 changes vs R3 (63us, VALUBusy 38%, 6.4e6 conflicts):
//  1. Parity replication: each 64B table row stored twice per 128B LDS line
//     (offsets 0 and 64). Lane picks parity p=(lane>>2)&1 and chunk
//     c=(q+lane)&3 -> every 8 consecutive lanes cover all 8 bank-spans of
//     the 128B period exactly once, independent of token data. Removes the
//     data-dependent parity clumping (R3's 6.3 vs R2's 4.0 cyc/instr).
//  2. Explicit load batching (template<K,N,P0,TB> with compile-time indices
//     only -- rule #20) to hold 10-20 ds_read_b128 in flight; R3's VGPR=48
//     shows the compiler kept ~3. __launch_bounds__(512,2) raises the cap;
//     occupancy is work-limited at 8 waves/CU (grid == 1 block/CU) anyway.

#define VOCABSZ 67
#define EMBSZ   32
#define NCH     32
#define NFEAT   96
#define SEQL    16
#define BATCH   131072
#define NTAB    9
#define NENT    (NTAB * VOCABSZ)           // 603 table entries
#define TABU    (NENT * NCH / 2)           // 9648 u32 words of f16 tables
#define PWOFF   TABU                       // packed pw follows tables in ws
#define NFP     (NFEAT / 2)                // 48 feature pairs
#define NPW     (NFEAT * NFP)              // 4608 packed pw words
#define LDSB    (NENT * 128)               // 77184 B replicated tables
#define TSTRB   8576                       // 67*128 B per table

typedef _Float16 v2h __attribute__((ext_vector_type(2)));
typedef _Float16 v8h __attribute__((ext_vector_type(8)));

__device__ __forceinline__ unsigned packh2(float a, float b) {
    v2h p; p[0] = (_Float16)a; p[1] = (_Float16)b;
    return __builtin_bit_cast(unsigned, p);
}

__device__ __forceinline__ float dot2acc(v2h a, v2h b, float c) {
#if __has_builtin(__builtin_amdgcn_fdot2)
    return __builtin_amdgcn_fdot2(a, b, c, false);   // v_dot2_f32_f16
#else
    return c + (float)a[0] * (float)b[0] + (float)a[1] * (float)b[1];
#endif
}

// ------------- kernel 1: f16 tables + packed pw into d_ws ------------------
__global__ __launch_bounds__(256) void build_tables(
    const float* __restrict__ embed,
    const float* __restrict__ w2, const float* __restrict__ b2,
    const float* __restrict__ w3, const float* __restrict__ b3,
    const float* __restrict__ w4, const float* __restrict__ b4,
    const float* __restrict__ pw,
    unsigned* __restrict__ ws)
{
    int idx = blockIdx.x * 256 + threadIdx.x;
    if (idx < TABU) {                      // one half2 (2 channels) per thread
        int cp = idx & 15;                 // channel pair 0..15
        int t  = idx >> 4;                 // j*67 + v
        int j  = t / VOCABSZ;
        int v  = t - j * VOCABSZ;
        const float* w; const float* bias; int k, h;
        if (j < 2)      { w = w2; k = 2; h = j;     bias = (h == 0) ? b2 : nullptr; }
        else if (j < 5) { w = w3; k = 3; h = j - 2; bias = (h == 0) ? b3 : nullptr; }
        else            { w = w4; k = 4; h = j - 5; bias = (h == 0) ? b4 : nullptr; }
        int c0 = 2 * cp;
        float a0 = bias ? bias[c0]     : 0.0f;
        float a1 = bias ? bias[c0 + 1] : 0.0f;
        if (v != 0) {                      // padding_idx=0: row 0 is zeros
            #pragma unroll
            for (int e = 0; e < EMBSZ; ++e) {
                float ev = embed[v * EMBSZ + e];
                a0 += ev * w[((c0    ) * EMBSZ + e) * k + h];
                a1 += ev * w[((c0 + 1) * EMBSZ + e) * k + h];
            }
        }
        ws[t * 16 + cp] = packh2(a0, a1);
    } else if (idx < TABU + NPW) {         // packed pw: pwh[o][fp]
        int i  = idx - TABU;
        int o  = i / NFP;
        int fp = i - o * NFP;
        ws[PWOFF + i] = packh2(pw[o * NFEAT + 2 * fp], pw[o * NFEAT + 2 * fp + 1]);
    }
}

// ------------- kernel 2: fused conv-as-lookup + max + projection -----------
__device__ __forceinline__ void unrot(v2h (&m)[16], bool r1, bool r2) {
    // canon group g = slot (g - rot) & 3 (groups of 4 half2 = one 16B chunk)
    v2h t[16];
    #pragma unroll
    for (int j = 0; j < 4; ++j) {
        t[0 + j]  = r1 ? m[12 + j] : m[0 + j];
        t[4 + j]  = r1 ? m[0 + j]  : m[4 + j];
        t[8 + j]  = r1 ? m[4 + j]  : m[8 + j];
        t[12 + j] = r1 ? m[8 + j]  : m[12 + j];
    }
    #pragma unroll
    for (int j = 0; j < 4; ++j) {
        m[0 + j]  = r2 ? t[8 + j]  : t[0 + j];
        m[4 + j]  = r2 ? t[12 + j] : t[4 + j];
        m[8 + j]  = r2 ? t[0 + j]  : t[8 + j];
        m[12 + j] = r2 ? t[4 + j]  : t[12 + j];
    }
}

#define MAXACC(M, Q, S) \
    M[4*(Q)+0] = __builtin_elementwise_max(M[4*(Q)+0], __builtin_shufflevector(S, S, 0, 1)); \
    M[4*(Q)+1] = __builtin_elementwise_max(M[4*(Q)+1], __builtin_shufflevector(S, S, 2, 3)); \
    M[4*(Q)+2] = __builtin_elementwise_max(M[4*(Q)+2], __builtin_shufflevector(S, S, 4, 5)); \
    M[4*(Q)+3] = __builtin_elementwise_max(M[4*(Q)+3], __builtin_shufflevector(S, S, 6, 7));

// One batch of N conv positions for a K-tap conv whose first table starts at
// byte TB. All array indices compile-time (P0, u, h are constexpr after
// template expansion + unroll) -- no scratch. Loads issue N at a time.
template<int K, int N, int P0, int TB>
__device__ __forceinline__ void convbatch(const char* __restrict__ base,
                                          const int (&ap)[16],
                                          v2h (&m)[16], int q)
{
    v8h s[N];
    #pragma unroll
    for (int u = 0; u < N; ++u)
        s[u] = *reinterpret_cast<const v8h*>(base + TB + ap[P0 + u]);
    #pragma unroll
    for (int h = 1; h < K; ++h) {
        v8h t[N];
        #pragma unroll
        for (int u = 0; u < N; ++u)
            t[u] = *reinterpret_cast<const v8h*>(base + TB + h * TSTRB + ap[P0 + u + h]);
        #pragma unroll
        for (int u = 0; u < N; ++u) s[u] = s[u] + t[u];
    }
    #pragma unroll
    for (int u = 0; u < N; ++u) { MAXACC(m, q, s[u]) }
}

__global__ __launch_bounds__(512, 2) void fused_cnn(
    const int*      __restrict__ x,
    const unsigned* __restrict__ ws,
    const float*    __restrict__ pb,
    float*          __restrict__ out)
{
    extern __shared__ __align__(16) char ldsraw[];
    const int tid = threadIdx.x;
    {   // stage + replicate: 2412 source float4 -> 2 LDS copies each.
        // c-swizzle (i+t)&3 decorrelates write banks a little; bijective.
        const float4* s4 = reinterpret_cast<const float4*>(ws);
        float4* d4 = reinterpret_cast<float4*>(ldsraw);
        #pragma unroll
        for (int i0 = 0; i0 < 2560; i0 += 512) {
            int i = i0 + tid;
            if (i < 2412) {
                int t = i >> 2;
                int c = (i + t) & 3;
                float4 v = s4[t * 4 + c];
                d4[t * 8 + c]     = v;   // parity 0
                d4[t * 8 + 4 + c] = v;   // parity 1 (+64 B)
            }
        }
    }
    __syncthreads();

    const int row = blockIdx.x * 512 + tid;      // grid exact: 256*512 = B
    const int rot = tid & 3;                     // chunk rotation
    const int par = (tid & 4) << 4;              // parity: 0 or 64 bytes
    const char* base = ldsraw;

    const int4* xp = reinterpret_cast<const int4*>(x + row * SEQL);
    int4 q0 = xp[0], q1 = xp[1], q2 = xp[2], q3 = xp[3];
    int vb[16];                                   // byte offset of entry row
    vb[ 0] = q0.x << 7; vb[ 1] = q0.y << 7; vb[ 2] = q0.z << 7; vb[ 3] = q0.w << 7;
    vb[ 4] = q1.x << 7; vb[ 5] = q1.y << 7; vb[ 6] = q1.z << 7; vb[ 7] = q1.w << 7;
    vb[ 8] = q2.x << 7; vb[ 9] = q2.y << 7; vb[10] = q2.z << 7; vb[11] = q2.w << 7;
    vb[12] = q3.x << 7; vb[13] = q3.y << 7; vb[14] = q3.z << 7; vb[15] = q3.w << 7;

    v2h m2[16], m3[16], m4[16];
    #pragma unroll
    for (int i = 0; i < 16; ++i) { m2[i] = 0; m3[i] = 0; m4[i] = 0; }

    #pragma unroll
    for (int q = 0; q < 4; ++q) {                 // 16B chunk step, lane-rotated
        const int co = (((q + rot) & 3) << 4) + par;
        int ap[16];
        #pragma unroll
        for (int p = 0; p < 16; ++p) ap[p] = vb[p] + co;

        // conv2: tables 0,1 ; 15 positions
        convbatch<2, 5,  0, 0 * TSTRB>(base, ap, m2, q);
        convbatch<2, 5,  5, 0 * TSTRB>(base, ap, m2, q);
        convbatch<2, 5, 10, 0 * TSTRB>(base, ap, m2, q);
        // conv3: tables 2,3,4 ; 14 positions
        convbatch<3, 5,  0, 2 * TSTRB>(base, ap, m3, q);
        convbatch<3, 5,  5, 2 * TSTRB>(base, ap, m3, q);
        convbatch<3, 4, 10, 2 * TSTRB>(base, ap, m3, q);
        // conv4: tables 5,6,7,8 ; 13 positions
        convbatch<4, 5,  0, 5 * TSTRB>(base, ap, m4, q);
        convbatch<4, 5,  5, 5 * TSTRB>(base, ap, m4, q);
        convbatch<4, 3, 10, 5 * TSTRB>(base, ap, m4, q);
    }

    const bool r1 = (rot & 1) != 0, r2b = (rot & 2) != 0;
    unrot(m2, r1, r2b);
    unrot(m3, r1, r2b);
    unrot(m4, r1, r2b);

    // projection: f32 acc, v_dot2_f32_f16; pw/pb wave-uniform -> s_load.
    const unsigned* __restrict__ pwh = ws + PWOFF;
    float* orow = out + (size_t)row * NFEAT;
    #pragma unroll 1
    for (int ob = 0; ob < NFEAT; ob += 8) {
        float acc[8];
        #pragma unroll
        for (int k = 0; k < 8; ++k) acc[k] = pb[ob + k];
        #pragma unroll
        for (int fp = 0; fp < NFP; ++fp) {
            v2h fv = (fp < 16) ? m2[fp] : ((fp < 32) ? m3[fp - 16] : m4[fp - 32]);
            #pragma unroll
            for (int k = 0; k < 8; ++k) {
                v2h wv = __builtin_bit_cast(v2h, pwh[(ob + k) * NFP + fp]);
                acc[k] = dot2acc(fv, wv, acc[k]);
            }
        }
        float4 o0 = make_float4(fmaxf(acc[0], 0.f), fmaxf(acc[1], 0.f),
                                fmaxf(acc[2], 0.f), fmaxf(acc[3], 0.f));
        float4 o1 = make_float4(fmaxf(acc[4], 0.f), fmaxf(acc[5], 0.f),
                                fmaxf(acc[6], 0.f), fmaxf(acc[7], 0.f));
        *reinterpret_cast<float4*>(orow + ob)     = o0;
        *reinterpret_cast<float4*>(orow + ob + 4) = o1;
    }
}

extern "C" void kernel_launch(void* const* d_in, const int* in_sizes, int n_in,
                              void* d_out, int out_size, void* d_ws, size_t ws_size,
                              hipStream_t stream)
{
    const int*   x     = (const int*)  d_in[0];
    const float* embed = (const float*)d_in[1];
    const float* w2    = (const float*)d_in[2];
    const float* b2    = (const float*)d_in[3];
    const float* w3    = (const float*)d_in[4];
    const float* b3    = (const float*)d_in[5];
    const float* w4    = (const float*)d_in[6];
    const float* b4    = (const float*)d_in[7];
    const float* pw    = (const float*)d_in[8];
    const float* pb    = (const float*)d_in[9];
    float* out = (float*)d_out;
    unsigned* ws = (unsigned*)d_ws;      // 9648 + 4608 u32 = 57 KB used

    build_tables<<<(TABU + NPW + 255) / 256, 256, 0, stream>>>(
        embed, w2, b2, w3, b3, w4, b4, pw, ws);

    (void)hipFuncSetAttribute((const void*)fused_cnn,
                              hipFuncAttributeMaxDynamicSharedMemorySize,
                              LDSB);
    fused_cnn<<<BATCH / 512, 512, LDSB, stream>>>(x, ws, pb, out);
}